// Round 4
// baseline (515.709 us; speedup 1.0000x reference)
//
#include <hip/hip_runtime.h>
#include <cstdint>
#include <cstddef>

#define TSTEPS 8
#define D 64

static __device__ __forceinline__ unsigned short f2bf(float f) {
    unsigned int u = __float_as_uint(f);
    return (unsigned short)((u + 0x7FFFu + ((u >> 16) & 1u)) >> 16);   // RNE
}
static __device__ __forceinline__ float bf2f(unsigned short h) {
    return __uint_as_float(((unsigned int)h) << 16);
}

// ---------------------------------------------------------------------------
// A1: per-(dst,t0) histogram. The atomic's return value IS the edge's rank
// within its bin -> the bucket pass needs no atomics.
// t0 = #{t : ntime[t] < etime}; edge active for t in [t0, 8). t0==8 dropped.
// ---------------------------------------------------------------------------
__global__ __launch_bounds__(256) void hist_kernel(
    const int* __restrict__ dst, const float* __restrict__ etime,
    const float* __restrict__ ntime, int E,
    int* __restrict__ cnt, unsigned int* __restrict__ keyA,
    unsigned int* __restrict__ rankA)
{
    int e = blockIdx.x * 256 + threadIdx.x;
    if (e >= E) return;
    float et = etime[e];
    int t0 = 0;
#pragma unroll
    for (int t = 0; t < TSTEPS; t++) t0 += (ntime[t] < et) ? 1 : 0;
    if (t0 < TSTEPS) {
        unsigned int key = ((unsigned int)dst[e] << 3) | (unsigned int)t0;
        unsigned int r = (unsigned int)atomicAdd(&cnt[key], 1);
        keyA[e] = key;
        rankA[e] = r;
    } else {
        keyA[e] = 0xFFFFFFFFu;
    }
}

// ---------------------------------------------------------------------------
// A2: hierarchical exclusive scan over cnt[0..n) (n = N*8)
// ---------------------------------------------------------------------------
__global__ __launch_bounds__(256) void reduce_kernel(const int* __restrict__ cnt,
                                                     int* __restrict__ sums, int n) {
    __shared__ int red[256];
    int tid = threadIdx.x;
    int base = blockIdx.x * 1024 + tid * 4;
    int tot = 0;
#pragma unroll
    for (int j = 0; j < 4; j++) { int i = base + j; tot += (i < n) ? cnt[i] : 0; }
    red[tid] = tot;
    __syncthreads();
    for (int s = 128; s > 0; s >>= 1) {
        if (tid < s) red[tid] += red[tid + s];
        __syncthreads();
    }
    if (tid == 0) sums[blockIdx.x] = red[0];
}

__global__ __launch_bounds__(256) void scanwrite_kernel(const int* __restrict__ cnt,
                                                        const int* __restrict__ sums,
                                                        int* __restrict__ rowptr, int n) {
    __shared__ int buf[256];
    int tid = threadIdx.x;
    int base = blockIdx.x * 1024 + tid * 4;
    int v[4];
    int tot = 0;
#pragma unroll
    for (int j = 0; j < 4; j++) { int i = base + j; v[j] = (i < n) ? cnt[i] : 0; tot += v[j]; }

    buf[tid] = tot;
    __syncthreads();
    for (int off = 1; off < 256; off <<= 1) {
        int t = (tid >= off) ? buf[tid - off] : 0;
        __syncthreads();
        buf[tid] += t;
        __syncthreads();
    }
    int exclThread = buf[tid] - tot;

    int bp = 0;
    for (int j = 0; j < blockIdx.x; j++) bp += sums[j];   // uniform scalar loads

    int running = bp + exclThread;
#pragma unroll
    for (int j = 0; j < 4; j++) {
        int i = base + j;
        if (i < n) { rowptr[i] = running; running += v[j]; }
    }
    if (blockIdx.x == (int)gridDim.x - 1 && tid == 255) rowptr[n] = running;  // total
}

// ---------------------------------------------------------------------------
// A3: atomic-free bucket fill: meta[rowptr[key]+rank] = (src, weight)
// ---------------------------------------------------------------------------
__global__ __launch_bounds__(256) void bucket_kernel(
    const int* __restrict__ src, const float* __restrict__ ew, int E,
    const unsigned int* __restrict__ keyA, const unsigned int* __restrict__ rankA,
    const int* __restrict__ rowptr, uint2* __restrict__ meta)
{
    int e = blockIdx.x * 256 + threadIdx.x;
    if (e >= E) return;
    unsigned int key = keyA[e];
    if (key == 0xFFFFFFFFu) return;
    int p = rowptr[key] + (int)rankA[e];
    uint2 m;
    m.x = (unsigned int)src[e];
    m.y = __float_as_uint(ew[e]);
    meta[p] = m;
}

// ---------------------------------------------------------------------------
// x -> bf16 copy (halves gather read bytes)
// ---------------------------------------------------------------------------
__global__ __launch_bounds__(256) void cvt_kernel(const float* __restrict__ x,
                                                  unsigned short* __restrict__ xb,
                                                  long n4) {
    long i = (long)blockIdx.x * blockDim.x + threadIdx.x;
    if (i >= n4) return;
    float4 v = ((const float4*)x)[i];
    ushort4 u;
    u.x = f2bf(v.x); u.y = f2bf(v.y); u.z = f2bf(v.z); u.w = f2bf(v.w);
    ((ushort4*)xb)[i] = u;
}

// ---------------------------------------------------------------------------
// B (fused, t-outer): per node, for each t the active edges are the prefix
// [rowptr[n*8], rowptr[n*8+t+1]) of the t0-sorted segment; all feature loads
// for a given t hit ONE 6.4 MB plane -> L2-resident working set.
// One wave per node: 4 edge groups x 16 lanes (ushort4/float4 per lane),
// 2-deep edge unroll (8 edges in flight). Then shuffle-reduce + fused linear.
// ---------------------------------------------------------------------------
template<bool USE_BF16>
__global__ __launch_bounds__(256) void fused_gather_kernel(
    const float* __restrict__ xf, const unsigned short* __restrict__ xb,
    const uint2* __restrict__ meta, const int* __restrict__ rowptr,
    const float* __restrict__ W, const float* __restrict__ b,
    float* __restrict__ out, int N)
{
    __shared__ float Wlds[64 * 64];           // 16 KB
    __shared__ float aggS[4][TSTEPS][64];     // 8 KB

    int tid = threadIdx.x;
#pragma unroll
    for (int i = 0; i < 16; i++) Wlds[tid + i * 256] = W[tid + i * 256];
    __syncthreads();

    int wslot = tid >> 6;
    int lane  = tid & 63;
    int g = lane >> 4;        // edge group 0..3
    int q = lane & 15;        // feature quad within row
    int n = blockIdx.x * 4 + wslot;

    const size_t plane = (size_t)N * D;        // floats per t-plane

    float4 acc[TSTEPS];
#pragma unroll
    for (int t = 0; t < TSTEPS; t++) acc[t] = make_float4(0.f, 0.f, 0.f, 0.f);

    if (n < N) {
        int rbase = n * 8;
        int base = rowptr[rbase];
#pragma unroll
        for (int t = 0; t < TSTEPS; t++) {
            int end = rowptr[rbase + t + 1];
            if (USE_BF16) {
                const unsigned short* xp = xb + (size_t)t * plane + q * 4;
                for (int p = base; p < end; p += 8) {
                    int i0 = p + g, i1 = p + g + 4;
                    if (i0 < end) {
                        uint2 m = meta[i0];
                        float w = __uint_as_float(m.y);
                        ushort4 u = *reinterpret_cast<const ushort4*>(xp + ((size_t)m.x << 6));
                        acc[t].x = fmaf(bf2f(u.x), w, acc[t].x);
                        acc[t].y = fmaf(bf2f(u.y), w, acc[t].y);
                        acc[t].z = fmaf(bf2f(u.z), w, acc[t].z);
                        acc[t].w = fmaf(bf2f(u.w), w, acc[t].w);
                    }
                    if (i1 < end) {
                        uint2 m = meta[i1];
                        float w = __uint_as_float(m.y);
                        ushort4 u = *reinterpret_cast<const ushort4*>(xp + ((size_t)m.x << 6));
                        acc[t].x = fmaf(bf2f(u.x), w, acc[t].x);
                        acc[t].y = fmaf(bf2f(u.y), w, acc[t].y);
                        acc[t].z = fmaf(bf2f(u.z), w, acc[t].z);
                        acc[t].w = fmaf(bf2f(u.w), w, acc[t].w);
                    }
                }
            } else {
                const float4* xp = reinterpret_cast<const float4*>(xf + (size_t)t * plane) + q;
                for (int p = base; p < end; p += 8) {
                    int i0 = p + g, i1 = p + g + 4;
                    if (i0 < end) {
                        uint2 m = meta[i0];
                        float w = __uint_as_float(m.y);
                        float4 v = xp[(size_t)m.x << 4];
                        acc[t].x = fmaf(v.x, w, acc[t].x);
                        acc[t].y = fmaf(v.y, w, acc[t].y);
                        acc[t].z = fmaf(v.z, w, acc[t].z);
                        acc[t].w = fmaf(v.w, w, acc[t].w);
                    }
                    if (i1 < end) {
                        uint2 m = meta[i1];
                        float w = __uint_as_float(m.y);
                        float4 v = xp[(size_t)m.x << 4];
                        acc[t].x = fmaf(v.x, w, acc[t].x);
                        acc[t].y = fmaf(v.y, w, acc[t].y);
                        acc[t].z = fmaf(v.z, w, acc[t].z);
                        acc[t].w = fmaf(v.w, w, acc[t].w);
                    }
                }
            }
        }
    }

    // reduce the 4 edge-groups: every lane ends with full sum for its quad
#pragma unroll
    for (int t = 0; t < TSTEPS; t++) {
        acc[t].x += __shfl_xor(acc[t].x, 16); acc[t].y += __shfl_xor(acc[t].y, 16);
        acc[t].z += __shfl_xor(acc[t].z, 16); acc[t].w += __shfl_xor(acc[t].w, 16);
        acc[t].x += __shfl_xor(acc[t].x, 32); acc[t].y += __shfl_xor(acc[t].y, 32);
        acc[t].z += __shfl_xor(acc[t].z, 32); acc[t].w += __shfl_xor(acc[t].w, 32);
    }

    if (lane < 16) {
#pragma unroll
        for (int t = 0; t < TSTEPS; t++)
            *reinterpret_cast<float4*>(&aggS[wslot][t][lane * 4]) = acc[t];
    }
    __syncthreads();   // every wave reaches this (no early returns)

    // transform: out[t][lane] = b[lane] + sum_k agg[t][k] * W[k][lane]
    float o[TSTEPS];
    float bias = b[lane];
#pragma unroll
    for (int t = 0; t < TSTEPS; t++) o[t] = bias;

    for (int kc = 0; kc < 16; kc++) {
        float w0 = Wlds[(4 * kc + 0) * 64 + lane];
        float w1 = Wlds[(4 * kc + 1) * 64 + lane];
        float w2 = Wlds[(4 * kc + 2) * 64 + lane];
        float w3 = Wlds[(4 * kc + 3) * 64 + lane];
#pragma unroll
        for (int t = 0; t < TSTEPS; t++) {
            float4 a = *reinterpret_cast<const float4*>(&aggS[wslot][t][4 * kc]);
            o[t] = fmaf(a.x, w0, fmaf(a.y, w1, fmaf(a.z, w2, fmaf(a.w, w3, o[t]))));
        }
    }

    if (n < N) {
        size_t ob = (size_t)n * D + lane;
#pragma unroll
        for (int t = 0; t < TSTEPS; t++) out[(size_t)t * plane + ob] = o[t];
    }
}

// ---------------------------------------------------------------------------
extern "C" void kernel_launch(void* const* d_in, const int* in_sizes, int n_in,
                              void* d_out, int out_size, void* d_ws, size_t ws_size,
                              hipStream_t stream)
{
    const float* x     = (const float*)d_in[0];
    const int*   eidx  = (const int*)d_in[1];
    const float* etime = (const float*)d_in[2];
    const float* ntime = (const float*)d_in[3];
    const float* ew    = (const float*)d_in[4];
    const float* W     = (const float*)d_in[5];
    const float* b     = (const float*)d_in[6];
    float* out = (float*)d_out;

    const int T = in_sizes[3];             // 8
    const int E = in_sizes[1] / 2;         // 800000
    const int N = in_sizes[0] / (T * D);   // 50000
    const int N8 = N * 8;

    const int* src = eidx;
    const int* dst = eidx + E;

    int nb = (N8 + 1023) / 1024;

    // workspace layout (key/rank overlay the xb region; dead before cvt runs)
    char* base = (char*)d_ws;
    uint2* meta   = (uint2*)base;                          // 8E
    int*   cnt    = (int*)(base + 8ll * E);                // 4*N8
    int*   rowptr = cnt + N8;                              // 4*(N8+1)
    int*   sums   = rowptr + N8 + 1;                       // 4*nb
    size_t offK = 8ll * E + 4ll * (2ll * N8 + 1 + nb);
    offK = (offK + 15) & ~(size_t)15;
    unsigned int* keyA  = (unsigned int*)(base + offK);    // 4E
    unsigned int* rankA = keyA + E;                        // 4E
    unsigned short* xb  = (unsigned short*)(base + offK);  // 2*T*N*D (overlay)

    size_t xbBytes = 2ll * T * N * D;
    size_t krBytes = 8ll * E;
    size_t needB = offK + (xbBytes > krBytes ? xbBytes : krBytes);
    bool useBf16 = (ws_size >= needB);

    hipMemsetAsync(cnt, 0, (size_t)N8 * sizeof(int), stream);

    hist_kernel<<<(E + 255) / 256, 256, 0, stream>>>(dst, etime, ntime, E,
                                                     cnt, keyA, rankA);
    reduce_kernel<<<nb, 256, 0, stream>>>(cnt, sums, N8);
    scanwrite_kernel<<<nb, 256, 0, stream>>>(cnt, sums, rowptr, N8);
    bucket_kernel<<<(E + 255) / 256, 256, 0, stream>>>(src, ew, E, keyA, rankA,
                                                       rowptr, meta);

    if (useBf16) {
        long n4 = (long)T * N * D / 4;
        cvt_kernel<<<(int)((n4 + 255) / 256), 256, 0, stream>>>(x, xb, n4);
        fused_gather_kernel<true><<<(N + 3) / 4, 256, 0, stream>>>(
            x, xb, meta, rowptr, W, b, out, N);
    } else {
        fused_gather_kernel<false><<<(N + 3) / 4, 256, 0, stream>>>(
            x, xb, meta, rowptr, W, b, out, N);
    }
}

// Round 7
// 466.946 us; speedup vs baseline: 1.1044x; 1.1044x over previous
//
#include <hip/hip_runtime.h>
#include <cstdint>
#include <cstddef>

#define TSTEPS 8
#define D 64

static __device__ __forceinline__ unsigned short f2bf(float f) {
    unsigned int u = __float_as_uint(f);
    return (unsigned short)((u + 0x7FFFu + ((u >> 16) & 1u)) >> 16);   // RNE
}
static __device__ __forceinline__ float bf2f(unsigned short h) {
    return __uint_as_float(((unsigned int)h) << 16);
}

// ---------------------------------------------------------------------------
// P1 (fused): block-role split.
//   blocks [0, histBlocks): per-dst histogram; atomic's return IS the edge's
//     rank within its dst bin (bucket pass becomes atomic-free).
//   blocks [histBlocks, ...): x [T,N,D] f32  ->  xb [N,T,D] bf16 transpose.
//     Node-major layout makes each edge's active rows t0..7 ONE contiguous
//     run (<=1 KB) in the gather.
// ---------------------------------------------------------------------------
__global__ __launch_bounds__(256) void prep_kernel(
    const float* __restrict__ x, unsigned short* __restrict__ xb,
    const int* __restrict__ dst, const float* __restrict__ etime,
    const float* __restrict__ ntime,
    int* __restrict__ cnt, unsigned short* __restrict__ rankA,
    int E, int N, int histBlocks, int blocksPerPlane)
{
    int tid = threadIdx.x;
    if ((int)blockIdx.x < histBlocks) {
        int e = blockIdx.x * 256 + tid;
        if (e < E) {
            float et = etime[e];
            int t0 = 0;
#pragma unroll
            for (int t = 0; t < TSTEPS; t++) t0 += (ntime[t] < et) ? 1 : 0;
            if (t0 < TSTEPS)
                rankA[e] = (unsigned short)atomicAdd(&cnt[dst[e]], 1);
        }
    } else {
        int bb = blockIdx.x - histBlocks;
        int t  = bb / blocksPerPlane;
        int r  = bb - t * blocksPerPlane;
        int j  = r * 256 + tid;          // float4-index within plane (16 per row)
        int d4 = j & 15;
        int n  = j >> 4;
        if (n < N) {
            float4 v = ((const float4*)x)[((size_t)t * N + n) * 16 + d4];
            ushort4 u;
            u.x = f2bf(v.x); u.y = f2bf(v.y); u.z = f2bf(v.z); u.w = f2bf(v.w);
            ((ushort4*)xb)[(size_t)n * 128 + t * 16 + d4] = u;
        }
    }
}

// ---------------------------------------------------------------------------
// P2: hierarchical exclusive scan over cnt[0..N)
// ---------------------------------------------------------------------------
__global__ __launch_bounds__(256) void reduce_kernel(const int* __restrict__ cnt,
                                                     int* __restrict__ sums, int n) {
    __shared__ int red[256];
    int tid = threadIdx.x;
    int base = blockIdx.x * 1024 + tid * 4;
    int tot = 0;
#pragma unroll
    for (int j = 0; j < 4; j++) { int i = base + j; tot += (i < n) ? cnt[i] : 0; }
    red[tid] = tot;
    __syncthreads();
    for (int s = 128; s > 0; s >>= 1) {
        if (tid < s) red[tid] += red[tid + s];
        __syncthreads();
    }
    if (tid == 0) sums[blockIdx.x] = red[0];
}

__global__ __launch_bounds__(256) void scanwrite_kernel(const int* __restrict__ cnt,
                                                        const int* __restrict__ sums,
                                                        int* __restrict__ rowptr, int n) {
    __shared__ int buf[256];
    int tid = threadIdx.x;
    int base = blockIdx.x * 1024 + tid * 4;
    int v[4];
    int tot = 0;
#pragma unroll
    for (int j = 0; j < 4; j++) { int i = base + j; v[j] = (i < n) ? cnt[i] : 0; tot += v[j]; }

    buf[tid] = tot;
    __syncthreads();
    for (int off = 1; off < 256; off <<= 1) {
        int t = (tid >= off) ? buf[tid - off] : 0;
        __syncthreads();
        buf[tid] += t;
        __syncthreads();
    }
    int exclThread = buf[tid] - tot;

    int bp = 0;
    for (int j = 0; j < blockIdx.x; j++) bp += sums[j];   // uniform scalar loads (<=48 iters)

    int running = bp + exclThread;
#pragma unroll
    for (int j = 0; j < 4; j++) {
        int i = base + j;
        if (i < n) { rowptr[i] = running; running += v[j]; }
    }
    if (blockIdx.x == (int)gridDim.x - 1 && tid == 255) rowptr[n] = running;  // total stored
}

// ---------------------------------------------------------------------------
// P3: atomic-free bucket fill. meta[rowptr[dst]+rank] = (src<<3|t0, weight).
// t0 recomputed (deterministic, identical to prep) so dropped edges (t0==8)
// never touch rankA/meta.
// ---------------------------------------------------------------------------
__global__ __launch_bounds__(256) void bucket_kernel(
    const int* __restrict__ src, const int* __restrict__ dst,
    const float* __restrict__ etime, const float* __restrict__ ew,
    const float* __restrict__ ntime, int E,
    const unsigned short* __restrict__ rankA, const int* __restrict__ rowptr,
    uint2* __restrict__ meta)
{
    int e = blockIdx.x * 256 + threadIdx.x;
    if (e >= E) return;
    float et = etime[e];
    int t0 = 0;
#pragma unroll
    for (int t = 0; t < TSTEPS; t++) t0 += (ntime[t] < et) ? 1 : 0;
    if (t0 >= TSTEPS) return;
    int p = rowptr[dst[e]] + (int)rankA[e];
    uint2 m;
    m.x = ((unsigned int)src[e] << 3) | (unsigned int)t0;
    m.y = __float_as_uint(ew[e]);
    meta[p] = m;
}

// ---------------------------------------------------------------------------
// B (fused gather + linear), t-inner, node-major features.
// One wave per node: 4 edge groups x 16 lanes, 2-deep edge unroll.
// Per edge: contiguous run xb[src][t0..7][:] (up to 1 KB), predicated
// statically-unrolled t-loop into acc[t]. Shuffle-reduce + fused linear.
// ---------------------------------------------------------------------------
template<bool USE_BF16>
__global__ __launch_bounds__(256) void fused_gather_kernel(
    const float* __restrict__ xf, const unsigned short* __restrict__ xb,
    const uint2* __restrict__ meta, const int* __restrict__ rowptr,
    const float* __restrict__ W, const float* __restrict__ b,
    float* __restrict__ out, int N)
{
    __shared__ float Wlds[64 * 64];           // 16 KB
    __shared__ float aggS[4][TSTEPS][64];     // 8 KB

    int tid = threadIdx.x;
#pragma unroll
    for (int i = 0; i < 16; i++) Wlds[tid + i * 256] = W[tid + i * 256];
    __syncthreads();

    int wslot = tid >> 6;
    int lane  = tid & 63;
    int g = lane >> 4;        // edge group 0..3
    int q = lane & 15;        // feature quad within row
    int n = blockIdx.x * 4 + wslot;

    const size_t plane = (size_t)N * D;        // floats per t-plane (f32 path)

    float4 acc[TSTEPS];
#pragma unroll
    for (int t = 0; t < TSTEPS; t++) acc[t] = make_float4(0.f, 0.f, 0.f, 0.f);

    if (n < N) {
        int p0 = rowptr[n], p1 = rowptr[n + 1];
        for (int p = p0; p < p1; p += 8) {
            int i0 = p + g, i1 = p + g + 4;
            if (USE_BF16) {
                if (i0 < p1) {
                    uint2 m = meta[i0];
                    int t0 = (int)(m.x & 7u);
                    float w = __uint_as_float(m.y);
                    const unsigned short* xp = xb + ((size_t)(m.x >> 3) << 9) + (q << 2);
#pragma unroll
                    for (int t = 0; t < TSTEPS; t++) {
                        if (t >= t0) {
                            ushort4 u = *reinterpret_cast<const ushort4*>(xp + (t << 6));
                            acc[t].x = fmaf(bf2f(u.x), w, acc[t].x);
                            acc[t].y = fmaf(bf2f(u.y), w, acc[t].y);
                            acc[t].z = fmaf(bf2f(u.z), w, acc[t].z);
                            acc[t].w = fmaf(bf2f(u.w), w, acc[t].w);
                        }
                    }
                }
                if (i1 < p1) {
                    uint2 m = meta[i1];
                    int t0 = (int)(m.x & 7u);
                    float w = __uint_as_float(m.y);
                    const unsigned short* xp = xb + ((size_t)(m.x >> 3) << 9) + (q << 2);
#pragma unroll
                    for (int t = 0; t < TSTEPS; t++) {
                        if (t >= t0) {
                            ushort4 u = *reinterpret_cast<const ushort4*>(xp + (t << 6));
                            acc[t].x = fmaf(bf2f(u.x), w, acc[t].x);
                            acc[t].y = fmaf(bf2f(u.y), w, acc[t].y);
                            acc[t].z = fmaf(bf2f(u.z), w, acc[t].z);
                            acc[t].w = fmaf(bf2f(u.w), w, acc[t].w);
                        }
                    }
                }
            } else {
                if (i0 < p1) {
                    uint2 m = meta[i0];
                    int t0 = (int)(m.x & 7u);
                    float w = __uint_as_float(m.y);
                    const float4* xp = reinterpret_cast<const float4*>(
                        xf + (size_t)(m.x >> 3) * D) + q;
#pragma unroll
                    for (int t = 0; t < TSTEPS; t++) {
                        if (t >= t0) {
                            float4 v = xp[(size_t)t * (plane >> 2)];
                            acc[t].x = fmaf(v.x, w, acc[t].x);
                            acc[t].y = fmaf(v.y, w, acc[t].y);
                            acc[t].z = fmaf(v.z, w, acc[t].z);
                            acc[t].w = fmaf(v.w, w, acc[t].w);
                        }
                    }
                }
                if (i1 < p1) {
                    uint2 m = meta[i1];
                    int t0 = (int)(m.x & 7u);
                    float w = __uint_as_float(m.y);
                    const float4* xp = reinterpret_cast<const float4*>(
                        xf + (size_t)(m.x >> 3) * D) + q;
#pragma unroll
                    for (int t = 0; t < TSTEPS; t++) {
                        if (t >= t0) {
                            float4 v = xp[(size_t)t * (plane >> 2)];
                            acc[t].x = fmaf(v.x, w, acc[t].x);
                            acc[t].y = fmaf(v.y, w, acc[t].y);
                            acc[t].z = fmaf(v.z, w, acc[t].z);
                            acc[t].w = fmaf(v.w, w, acc[t].w);
                        }
                    }
                }
            }
        }
    }

    // reduce the 4 edge-groups: every lane ends with full sum for its quad
#pragma unroll
    for (int t = 0; t < TSTEPS; t++) {
        acc[t].x += __shfl_xor(acc[t].x, 16); acc[t].y += __shfl_xor(acc[t].y, 16);
        acc[t].z += __shfl_xor(acc[t].z, 16); acc[t].w += __shfl_xor(acc[t].w, 16);
        acc[t].x += __shfl_xor(acc[t].x, 32); acc[t].y += __shfl_xor(acc[t].y, 32);
        acc[t].z += __shfl_xor(acc[t].z, 32); acc[t].w += __shfl_xor(acc[t].w, 32);
    }

    if (lane < 16) {
#pragma unroll
        for (int t = 0; t < TSTEPS; t++)
            *reinterpret_cast<float4*>(&aggS[wslot][t][lane * 4]) = acc[t];
    }
    __syncthreads();   // every wave reaches this (no early returns)

    // transform: out[t][lane] = b[lane] + sum_k agg[t][k] * W[k][lane]
    float o[TSTEPS];
    float bias = b[lane];
#pragma unroll
    for (int t = 0; t < TSTEPS; t++) o[t] = bias;

    for (int kc = 0; kc < 16; kc++) {
        float w0 = Wlds[(4 * kc + 0) * 64 + lane];
        float w1 = Wlds[(4 * kc + 1) * 64 + lane];
        float w2 = Wlds[(4 * kc + 2) * 64 + lane];
        float w3 = Wlds[(4 * kc + 3) * 64 + lane];
#pragma unroll
        for (int t = 0; t < TSTEPS; t++) {
            float4 a = *reinterpret_cast<const float4*>(&aggS[wslot][t][4 * kc]);
            o[t] = fmaf(a.x, w0, fmaf(a.y, w1, fmaf(a.z, w2, fmaf(a.w, w3, o[t]))));
        }
    }

    if (n < N) {
        size_t ob = (size_t)n * D + lane;
#pragma unroll
        for (int t = 0; t < TSTEPS; t++) out[(size_t)t * plane + ob] = o[t];
    }
}

// ---------------------------------------------------------------------------
extern "C" void kernel_launch(void* const* d_in, const int* in_sizes, int n_in,
                              void* d_out, int out_size, void* d_ws, size_t ws_size,
                              hipStream_t stream)
{
    const float* x     = (const float*)d_in[0];
    const int*   eidx  = (const int*)d_in[1];
    const float* etime = (const float*)d_in[2];
    const float* ntime = (const float*)d_in[3];
    const float* ew    = (const float*)d_in[4];
    const float* W     = (const float*)d_in[5];
    const float* b     = (const float*)d_in[6];
    float* out = (float*)d_out;

    const int T = in_sizes[3];             // 8
    const int E = in_sizes[1] / 2;         // 800000
    const int N = in_sizes[0] / (T * D);   // 50000

    const int* src = eidx;
    const int* dst = eidx + E;

    int nb = (N + 1023) / 1024;

    // workspace layout
    char* base = (char*)d_ws;
    uint2* meta   = (uint2*)base;                             // 8E
    int*   cnt    = (int*)(base + 8ll * E);                   // 4N
    int*   rowptr = cnt + N;                                  // 4(N+1)
    int*   sums   = rowptr + N + 1;                           // 4*nb
    unsigned short* rankA = (unsigned short*)(sums + nb);     // 2E
    size_t offX = 8ll * E + 4ll * (2ll * N + 1 + nb) + 2ll * E;
    offX = (offX + 15) & ~(size_t)15;
    unsigned short* xb = (unsigned short*)(base + offX);      // 2*T*N*D
    size_t needB = offX + 2ll * (size_t)T * N * D;
    bool useBf16 = (ws_size >= needB);

    hipMemsetAsync(cnt, 0, (size_t)N * sizeof(int), stream);

    int histBlocks = (E + 255) / 256;
    int blocksPerPlane = (16 * N + 255) / 256;
    int prepGrid = useBf16 ? (histBlocks + T * blocksPerPlane) : histBlocks;

    prep_kernel<<<prepGrid, 256, 0, stream>>>(x, xb, dst, etime, ntime,
                                              cnt, rankA, E, N, histBlocks,
                                              blocksPerPlane);
    reduce_kernel<<<nb, 256, 0, stream>>>(cnt, sums, N);
    scanwrite_kernel<<<nb, 256, 0, stream>>>(cnt, sums, rowptr, N);
    bucket_kernel<<<histBlocks, 256, 0, stream>>>(src, dst, etime, ew, ntime, E,
                                                  rankA, rowptr, meta);

    if (useBf16) {
        fused_gather_kernel<true><<<(N + 3) / 4, 256, 0, stream>>>(
            x, xb, meta, rowptr, W, b, out, N);
    } else {
        fused_gather_kernel<false><<<(N + 3) / 4, 256, 0, stream>>>(
            x, xb, meta, rowptr, W, b, out, N);
    }
}